// Round 1
// baseline (720.584 us; speedup 1.0000x reference)
//
#include <hip/hip_runtime.h>
#include <math.h>

#define NEG_SLOPE 0.2f

__device__ __forceinline__ float leaky(float x) { return x > 0.f ? x : NEG_SLOPE * x; }
// exp(a-b) that returns 0 when a == -inf (avoids -inf - -inf = NaN)
__device__ __forceinline__ float expdiff(float a, float b) {
    return (a == -INFINITY) ? 0.f : __expf(a - b);
}

// ---------------- CSR build ----------------
__global__ void deg_kernel(const int* __restrict__ dst, int* __restrict__ deg, int E) {
    int e = blockIdx.x * 256 + threadIdx.x;
    if (e < E) atomicAdd(&deg[dst[e]], 1);
}

__global__ __launch_bounds__(256) void scan_block(const int* __restrict__ deg,
                                                  int* __restrict__ off,
                                                  int* __restrict__ bsum, int N) {
    __shared__ int sh[256];
    int t = threadIdx.x;
    int i = blockIdx.x * 256 + t;
    int v = (i < N) ? deg[i] : 0;
    sh[t] = v; __syncthreads();
    for (int s = 1; s < 256; s <<= 1) {
        int add = (t >= s) ? sh[t - s] : 0;
        __syncthreads();
        sh[t] += add;
        __syncthreads();
    }
    if (i < N) off[i] = sh[t] - v;        // exclusive
    if (t == 255) bsum[blockIdx.x] = sh[255];
}

__global__ __launch_bounds__(1024) void scan_aux(int* __restrict__ bsum, int nb) {
    __shared__ int sh[1024];
    int t = threadIdx.x;
    int v = (t < nb) ? bsum[t] : 0;
    sh[t] = v; __syncthreads();
    for (int s = 1; s < 1024; s <<= 1) {
        int add = (t >= s) ? sh[t - s] : 0;
        __syncthreads();
        sh[t] += add;
        __syncthreads();
    }
    if (t < nb) bsum[t] = sh[t] - v;      // exclusive
}

__global__ void scan_add(int* __restrict__ off, const int* __restrict__ bsum, int N) {
    int i = blockIdx.x * 256 + threadIdx.x;
    if (i < N) off[i] += bsum[blockIdx.x];
}

__global__ void scatter_kernel(const int* __restrict__ src, const int* __restrict__ dst,
                               const int* __restrict__ off, int* __restrict__ cur,
                               int* __restrict__ csr, int E) {
    int e = blockIdx.x * 256 + threadIdx.x;
    if (e < E) {
        int d = dst[e];
        int p = atomicAdd(&cur[d], 1);
        csr[off[d] + p] = src[e];
    }
}

// ---------------- GEMM1: h1 = x @ W1 (+ attention dots) ----------------
// block 256 (4 waves), each wave 4 rows, lane = out col (64)
__global__ __launch_bounds__(256) void gemm1_kernel(
    const float* __restrict__ x, const float* __restrict__ W1,
    const float* __restrict__ att_src, const float* __restrict__ att_dst,
    float* __restrict__ h1, float* __restrict__ a_src, float* __restrict__ a_dst, int N)
{
    __shared__ float Wl[128 * 64];
    int tid = threadIdx.x;
    for (int i = tid; i < 128 * 64; i += 256) Wl[i] = W1[i];
    __syncthreads();

    int lane = tid & 63, w = tid >> 6;
    int row0 = blockIdx.x * 16 + w * 4;
    if (row0 >= N) return;

    int r0 = row0, r1 = min(row0 + 1, N - 1), r2 = min(row0 + 2, N - 1), r3 = min(row0 + 3, N - 1);
    const float4* xr0 = (const float4*)(x + (size_t)r0 * 128);
    const float4* xr1 = (const float4*)(x + (size_t)r1 * 128);
    const float4* xr2 = (const float4*)(x + (size_t)r2 * 128);
    const float4* xr3 = (const float4*)(x + (size_t)r3 * 128);

    float acc0 = 0.f, acc1 = 0.f, acc2 = 0.f, acc3 = 0.f;
#pragma unroll 4
    for (int k4 = 0; k4 < 32; ++k4) {
        float4 va = xr0[k4], vb = xr1[k4], vc = xr2[k4], vd = xr3[k4];
        int kb = k4 * 256 + lane;
        float w0 = Wl[kb], w1 = Wl[kb + 64], w2 = Wl[kb + 128], w3 = Wl[kb + 192];
        acc0 = fmaf(va.x, w0, fmaf(va.y, w1, fmaf(va.z, w2, fmaf(va.w, w3, acc0))));
        acc1 = fmaf(vb.x, w0, fmaf(vb.y, w1, fmaf(vb.z, w2, fmaf(vb.w, w3, acc1))));
        acc2 = fmaf(vc.x, w0, fmaf(vc.y, w1, fmaf(vc.z, w2, fmaf(vc.w, w3, acc2))));
        acc3 = fmaf(vd.x, w0, fmaf(vd.y, w1, fmaf(vd.z, w2, fmaf(vd.w, w3, acc3))));
    }

    float asv = att_src[lane], adv = att_dst[lane];
    int row[4] = {row0, row0 + 1, row0 + 2, row0 + 3};
    float acc[4] = {acc0, acc1, acc2, acc3};
#pragma unroll
    for (int r = 0; r < 4; ++r) {
        if (row[r] >= N) break;
        float v = acc[r];
        h1[(size_t)row[r] * 64 + lane] = v;
        float ts = v * asv, td = v * adv;
        ts += __shfl_xor(ts, 1); ts += __shfl_xor(ts, 2); ts += __shfl_xor(ts, 4);
        td += __shfl_xor(td, 1); td += __shfl_xor(td, 2); td += __shfl_xor(td, 4);
        if ((lane & 7) == 0) {
            a_src[row[r] * 8 + (lane >> 3)] = ts;
            a_dst[row[r] * 8 + (lane >> 3)] = td;
        }
    }
}

// ---------------- layer-1 aggregate: softmax over incoming edges + feature gather ----------------
// one wave per node; pass1 lane = (i=lane>>3 edge-slot, h=lane&7); pass2 lane = feature (h=lane>>3)
__global__ __launch_bounds__(256) void agg1_kernel(
    const float* __restrict__ h1, const float* __restrict__ a_src, const float* __restrict__ a_dst,
    const int* __restrict__ off, const int* __restrict__ deg, const int* __restrict__ csr,
    const float* __restrict__ b1, float* __restrict__ helu, int N)
{
    int wid = (blockIdx.x * 256 + threadIdx.x) >> 6;
    int lane = threadIdx.x & 63;
    if (wid >= N) return;
    int n = wid;
    int o = off[n], d = deg[n];

    int h = lane & 7, i = lane >> 3;
    float adst = a_dst[n * 8 + h];
    float m, l;
    if (i == 0) { float es = leaky(a_src[n * 8 + h] + adst); m = es; l = 1.f; }
    else { m = -INFINITY; l = 0.f; }

    for (int base = 0; base < d; base += 64) {
        int idx = base + lane;
        int sv = (idx < d) ? csr[o + idx] : 0;
        int lim = min(64, d - base);
        int tmax = (lim + 7) >> 3;
        for (int t = 0; t < tmax; ++t) {
            int sl = i + 8 * t;
            int srcn = __shfl(sv, sl);
            if (sl < lim) {
                float e = leaky(a_src[srcn * 8 + h] + adst);
                float mn = fmaxf(m, e);
                l = l * expdiff(m, mn) + __expf(e - mn);
                m = mn;
            }
        }
    }
    // reduce (m,l) across the 8 edge-slots (same h)
    for (int s = 8; s < 64; s <<= 1) {
        float mo = __shfl_xor(m, s), lo = __shfl_xor(l, s);
        float mn = fmaxf(m, mo);
        l = l * expdiff(m, mn) + lo * expdiff(mo, mn);
        m = mn;
    }
    float inv = 1.f / l;

    // re-map to feature layout: h = lane>>3
    int hf = lane >> 3;
    float mh = __shfl(m, hf);
    float invh = __shfl(inv, hf);
    float adf = a_dst[n * 8 + hf];
    float esf = leaky(a_src[n * 8 + hf] + adf);
    float acc = expdiff(esf, mh) * invh * h1[(size_t)n * 64 + lane];   // self loop

    for (int base = 0; base < d; base += 64) {
        int idx = base + lane;
        int sv = (idx < d) ? csr[o + idx] : 0;
        int lim = min(64, d - base);
        for (int j = 0; j < lim; ++j) {
            int srcn = __shfl(sv, j);
            float e = leaky(a_src[srcn * 8 + hf] + adf);
            float alpha = __expf(e - mh) * invh;
            acc += alpha * h1[(size_t)srcn * 64 + lane];
        }
    }
    float v = acc + b1[lane];
    helu[(size_t)n * 64 + lane] = (v > 0.f) ? v : (__expf(v) - 1.f);   // ELU
}

// ---------------- GEMM2: h2 = helu @ W2 (+ scalar attention dots) ----------------
__global__ __launch_bounds__(256) void gemm2_kernel(
    const float* __restrict__ hin, const float* __restrict__ W2,
    const float* __restrict__ att_src2, const float* __restrict__ att_dst2,
    float* __restrict__ h2, float* __restrict__ a_src, float* __restrict__ a_dst, int N)
{
    __shared__ float Wl[64 * 40];
    int tid = threadIdx.x;
    for (int i = tid; i < 64 * 40; i += 256) Wl[i] = W2[i];
    __syncthreads();

    int lane = tid & 63, w = tid >> 6;
    int row0 = blockIdx.x * 16 + w * 4;
    if (row0 >= N) return;
    int col = (lane < 40) ? lane : 0;

    int r0 = row0, r1 = min(row0 + 1, N - 1), r2 = min(row0 + 2, N - 1), r3 = min(row0 + 3, N - 1);
    const float4* xr0 = (const float4*)(hin + (size_t)r0 * 64);
    const float4* xr1 = (const float4*)(hin + (size_t)r1 * 64);
    const float4* xr2 = (const float4*)(hin + (size_t)r2 * 64);
    const float4* xr3 = (const float4*)(hin + (size_t)r3 * 64);

    float acc0 = 0.f, acc1 = 0.f, acc2 = 0.f, acc3 = 0.f;
#pragma unroll 4
    for (int k4 = 0; k4 < 16; ++k4) {
        float4 va = xr0[k4], vb = xr1[k4], vc = xr2[k4], vd = xr3[k4];
        int kb = k4 * 160 + col;
        float w0 = Wl[kb], w1 = Wl[kb + 40], w2 = Wl[kb + 80], w3 = Wl[kb + 120];
        acc0 = fmaf(va.x, w0, fmaf(va.y, w1, fmaf(va.z, w2, fmaf(va.w, w3, acc0))));
        acc1 = fmaf(vb.x, w0, fmaf(vb.y, w1, fmaf(vb.z, w2, fmaf(vb.w, w3, acc1))));
        acc2 = fmaf(vc.x, w0, fmaf(vc.y, w1, fmaf(vc.z, w2, fmaf(vc.w, w3, acc2))));
        acc3 = fmaf(vd.x, w0, fmaf(vd.y, w1, fmaf(vd.z, w2, fmaf(vd.w, w3, acc3))));
    }

    float asv = (lane < 40) ? att_src2[lane] : 0.f;
    float adv = (lane < 40) ? att_dst2[lane] : 0.f;
    int row[4] = {row0, row0 + 1, row0 + 2, row0 + 3};
    float acc[4] = {acc0, acc1, acc2, acc3};
#pragma unroll
    for (int r = 0; r < 4; ++r) {
        if (row[r] >= N) break;
        float v = acc[r];
        if (lane < 40) h2[(size_t)row[r] * 40 + lane] = v;
        float ts = (lane < 40) ? v * asv : 0.f;
        float td = (lane < 40) ? v * adv : 0.f;
        for (int s = 1; s < 64; s <<= 1) { ts += __shfl_xor(ts, s); td += __shfl_xor(td, s); }
        if (lane == 0) { a_src[row[r]] = ts; a_dst[row[r]] = td; }
    }
}

// ---------------- layer-2 aggregate + bias + log_softmax ----------------
__global__ __launch_bounds__(256) void agg2_kernel(
    const float* __restrict__ h2, const float* __restrict__ a_src, const float* __restrict__ a_dst,
    const int* __restrict__ off, const int* __restrict__ deg, const int* __restrict__ csr,
    const float* __restrict__ b2, float* __restrict__ out, int N)
{
    int wid = (blockIdx.x * 256 + threadIdx.x) >> 6;
    int lane = threadIdx.x & 63;
    if (wid >= N) return;
    int n = wid;
    int o = off[n], d = deg[n];

    float adst = a_dst[n];
    float es = leaky(a_src[n] + adst);       // self loop
    float m = (lane == 0) ? es : -INFINITY;
    float l = (lane == 0) ? 1.f : 0.f;

    for (int base = 0; base < d; base += 64) {
        int idx = base + lane;
        if (idx < d) {
            int srcn = csr[o + idx];
            float e = leaky(a_src[srcn] + adst);
            float mn = fmaxf(m, e);
            l = l * expdiff(m, mn) + __expf(e - mn);
            m = mn;
        }
    }
    for (int s = 1; s < 64; s <<= 1) {
        float mo = __shfl_xor(m, s), lo = __shfl_xor(l, s);
        float mn = fmaxf(m, mo);
        l = l * expdiff(m, mn) + lo * expdiff(mo, mn);
        m = mn;
    }
    float inv = 1.f / l;

    float acc = 0.f;
    float alpha_s = expdiff(es, m) * inv;
    if (lane < 40) acc = alpha_s * h2[(size_t)n * 40 + lane];

    for (int base = 0; base < d; base += 64) {
        int idx = base + lane;
        int sv = (idx < d) ? csr[o + idx] : 0;
        float pv = 0.f;
        if (idx < d) {
            float e = leaky(a_src[sv] + adst);
            pv = __expf(e - m) * inv;
        }
        int lim = min(64, d - base);
        for (int j = 0; j < lim; ++j) {
            int srcn = __shfl(sv, j);
            float alpha = __shfl(pv, j);
            if (lane < 40) acc += alpha * h2[(size_t)srcn * 40 + lane];
        }
    }

    float v = (lane < 40) ? acc + b2[lane] : -INFINITY;
    float mx = v;
    for (int s = 1; s < 64; s <<= 1) mx = fmaxf(mx, __shfl_xor(mx, s));
    float ex = (lane < 40) ? __expf(v - mx) : 0.f;
    float se = ex;
    for (int s = 1; s < 64; s <<= 1) se += __shfl_xor(se, s);
    if (lane < 40) out[(size_t)n * 40 + lane] = v - mx - logf(se);
}

extern "C" void kernel_launch(void* const* d_in, const int* in_sizes, int n_in,
                              void* d_out, int out_size, void* d_ws, size_t ws_size,
                              hipStream_t stream) {
    const float* x        = (const float*)d_in[0];
    const int*   ei       = (const int*)d_in[1];
    const float* W1       = (const float*)d_in[2];
    const float* att_src1 = (const float*)d_in[3];
    const float* att_dst1 = (const float*)d_in[4];
    const float* b1       = (const float*)d_in[5];
    const float* W2       = (const float*)d_in[6];
    const float* att_src2 = (const float*)d_in[7];
    const float* att_dst2 = (const float*)d_in[8];
    const float* b2       = (const float*)d_in[9];
    float* out = (float*)d_out;

    int N = in_sizes[0] / 128;
    int E = in_sizes[1] / 2;
    const int* src = ei;
    const int* dst = ei + E;

    // workspace carve (all within d_ws)
    char* w = (char*)d_ws;
    auto alloc = [&](size_t bytes) { void* p = (void*)w; w += (bytes + 255) & ~(size_t)255; return p; };
    float* h1   = (float*)alloc((size_t)N * 64 * 4);
    float* helu = (float*)alloc((size_t)N * 64 * 4);
    float* as1  = (float*)alloc((size_t)N * 8 * 4);
    float* ad1  = (float*)alloc((size_t)N * 8 * 4);
    int*   degv = (int*)alloc((size_t)N * 4);
    int*   cur  = (int*)alloc((size_t)N * 4);
    int*   offv = (int*)alloc((size_t)(N + 1) * 4);
    int*   bsum = (int*)alloc(1024 * 4);
    int*   csr  = (int*)alloc((size_t)E * 4);
    // layer-2 buffers alias layer-1 ones that are dead by then:
    float* h2  = h1;          // agg1 finished reading h1 before gemm2 writes h2
    float* as2 = as1;         // as1/ad1 dead after agg1
    float* ad2 = ad1;

    hipMemsetAsync(degv, 0, (size_t)N * 4, stream);
    hipMemsetAsync(cur, 0, (size_t)N * 4, stream);

    int eb = (E + 255) / 256;
    int nb = (N + 255) / 256;
    deg_kernel<<<eb, 256, 0, stream>>>(dst, degv, E);
    scan_block<<<nb, 256, 0, stream>>>(degv, offv, bsum, N);
    scan_aux<<<1, 1024, 0, stream>>>(bsum, nb);
    scan_add<<<nb, 256, 0, stream>>>(offv, bsum, N);
    scatter_kernel<<<eb, 256, 0, stream>>>(src, dst, offv, cur, csr, E);

    gemm1_kernel<<<(N + 15) / 16, 256, 0, stream>>>(x, W1, att_src1, att_dst1, h1, as1, ad1, N);
    agg1_kernel<<<(N + 3) / 4, 256, 0, stream>>>(h1, as1, ad1, offv, degv, csr, b1, helu, N);
    gemm2_kernel<<<(N + 15) / 16, 256, 0, stream>>>(helu, W2, att_src2, att_dst2, h2, as2, ad2, N);
    agg2_kernel<<<(N + 3) / 4, 256, 0, stream>>>(h2, as2, ad2, offv, degv, csr, b2, out, N);
}

// Round 2
// 685.813 us; speedup vs baseline: 1.0507x; 1.0507x over previous
//
#include <hip/hip_runtime.h>
#include <math.h>

#define NEG_SLOPE 0.2f

__device__ __forceinline__ float leaky(float x) { return x > 0.f ? x : NEG_SLOPE * x; }

// ---------------- CSR build ----------------
__global__ void deg_kernel(const int* __restrict__ dst, int* __restrict__ deg, int E) {
    int e = blockIdx.x * 256 + threadIdx.x;
    if (e < E) atomicAdd(&deg[dst[e]], 1);
}

__global__ __launch_bounds__(256) void scan_block(const int* __restrict__ deg,
                                                  int* __restrict__ off,
                                                  int* __restrict__ bsum, int N) {
    __shared__ int sh[256];
    int t = threadIdx.x;
    int i = blockIdx.x * 256 + t;
    int v = (i < N) ? deg[i] : 0;
    sh[t] = v; __syncthreads();
    for (int s = 1; s < 256; s <<= 1) {
        int add = (t >= s) ? sh[t - s] : 0;
        __syncthreads();
        sh[t] += add;
        __syncthreads();
    }
    if (i < N) off[i] = sh[t] - v;        // exclusive
    if (t == 255) bsum[blockIdx.x] = sh[255];
}

__global__ __launch_bounds__(1024) void scan_aux(int* __restrict__ bsum, int nb) {
    __shared__ int sh[1024];
    int t = threadIdx.x;
    int v = (t < nb) ? bsum[t] : 0;
    sh[t] = v; __syncthreads();
    for (int s = 1; s < 1024; s <<= 1) {
        int add = (t >= s) ? sh[t - s] : 0;
        __syncthreads();
        sh[t] += add;
        __syncthreads();
    }
    if (t < nb) bsum[t] = sh[t] - v;      // exclusive
}

__global__ void scan_add(int* __restrict__ off, const int* __restrict__ bsum, int N) {
    int i = blockIdx.x * 256 + threadIdx.x;
    if (i < N) off[i] += bsum[blockIdx.x];
}

__global__ void scatter_kernel(const int* __restrict__ src, const int* __restrict__ dst,
                               const int* __restrict__ off, int* __restrict__ cur,
                               int* __restrict__ csr, int E) {
    int e = blockIdx.x * 256 + threadIdx.x;
    if (e < E) {
        int d = dst[e];
        int p = atomicAdd(&cur[d], 1);
        csr[off[d] + p] = src[e];
    }
}

// ---------------- GEMM1: h1 = x @ W1 (+ attention dots) ----------------
// block 256 (4 waves), each wave 8 rows, lane = out col (64)
// LDS holds W as float4 [k4][col] so the k-loop is one ds_read_b128 per k4.
__global__ __launch_bounds__(256) void gemm1_kernel(
    const float* __restrict__ x, const float* __restrict__ W1,
    const float* __restrict__ att_src, const float* __restrict__ att_dst,
    float* __restrict__ h1, float* __restrict__ a_src, float* __restrict__ a_dst, int N)
{
    __shared__ float4 Wl[32 * 64];
    int tid = threadIdx.x;
    for (int i = tid; i < 32 * 64; i += 256) {
        int k4 = i >> 6, c = i & 63;
        const float* wp = W1 + (size_t)(k4 * 4) * 64 + c;
        Wl[i] = make_float4(wp[0], wp[64], wp[128], wp[192]);
    }
    __syncthreads();

    int lane = tid & 63, w = tid >> 6;
    int row0 = blockIdx.x * 32 + w * 8;
    if (row0 >= N) return;
    int nrow = min(8, N - row0);

    const float4* xb = (const float4*)(x + (size_t)row0 * 128);
    int ro[8];
#pragma unroll
    for (int r = 0; r < 8; ++r) ro[r] = min(r, nrow - 1) * 32;

    float acc[8] = {0.f, 0.f, 0.f, 0.f, 0.f, 0.f, 0.f, 0.f};
#pragma unroll 2
    for (int k4 = 0; k4 < 32; ++k4) {
        float4 wv = Wl[k4 * 64 + lane];
#pragma unroll
        for (int r = 0; r < 8; ++r) {
            float4 xv = xb[ro[r] + k4];
            acc[r] = fmaf(xv.x, wv.x, fmaf(xv.y, wv.y, fmaf(xv.z, wv.z, fmaf(xv.w, wv.w, acc[r]))));
        }
    }

    float asv = att_src[lane], adv = att_dst[lane];
#pragma unroll
    for (int r = 0; r < 8; ++r) {
        if (r >= nrow) break;
        float v = acc[r];
        h1[(size_t)(row0 + r) * 64 + lane] = v;
        float ts = v * asv, td = v * adv;
        ts += __shfl_xor(ts, 1); ts += __shfl_xor(ts, 2); ts += __shfl_xor(ts, 4);
        td += __shfl_xor(td, 1); td += __shfl_xor(td, 2); td += __shfl_xor(td, 4);
        if ((lane & 7) == 0) {
            a_src[(row0 + r) * 8 + (lane >> 3)] = ts;
            a_dst[(row0 + r) * 8 + (lane >> 3)] = td;
        }
    }
}

// ---------------- layer-1 aggregate: SINGLE-PASS unnormalized softmax ----------------
// one wave per node. p computed in (edge,head) layout: ei=lane>>3 edge-slot, h8=lane&7.
// features accumulated in (head,feat) layout: hf=lane>>3, f=lane&7.
// out = (Σ_e p_e h[src_e] + p_self h[n]) / (Σ p) — identical to softmax, no max pass.
__global__ __launch_bounds__(256) void agg1_kernel(
    const float* __restrict__ h1, const float* __restrict__ a_src, const float* __restrict__ a_dst,
    const int* __restrict__ off, const int* __restrict__ deg, const int* __restrict__ csr,
    const float* __restrict__ b1, float* __restrict__ helu, int N)
{
    int wid = (blockIdx.x * 256 + threadIdx.x) >> 6;
    int lane = threadIdx.x & 63;
    if (wid >= N) return;
    int n = wid;
    int o = off[n], d = deg[n];
    int h8 = lane & 7;      // head in (edge,head) layout
    int ei = lane >> 3;     // edge slot
    int hf = lane >> 3;     // head in feature layout

    float adst = a_dst[n * 8 + h8];
    float p_self = __expf(leaky(a_src[n * 8 + h8] + adst));
    float s = (ei == 0) ? p_self : 0.f;
    float acc = __shfl(p_self, hf) * h1[(size_t)n * 64 + lane];   // self loop

    for (int base = 0; base < d; base += 64) {
        int idx = base + lane;
        int sv = (idx < d) ? csr[o + idx] : 0;
        int lim = min(64, d - base);
        for (int t = 0; t * 8 < lim; ++t) {
            int eidx = t * 8 + ei;
            int srcn = __shfl(sv, eidx);
            float p = 0.f;
            if (eidx < lim)
                p = __expf(leaky(a_src[srcn * 8 + h8] + adst));
            s += p;
            int jmax = min(8, lim - t * 8);
            for (int j = 0; j < jmax; ++j) {
                int sj = __shfl(sv, t * 8 + j);
                float alpha = __shfl(p, j * 8 + hf);
                acc = fmaf(alpha, h1[(size_t)sj * 64 + lane], acc);
            }
        }
    }
    // sum p over edge-slots (same head): flip ei bits
    s += __shfl_xor(s, 8); s += __shfl_xor(s, 16); s += __shfl_xor(s, 32);
    float sf = __shfl(s, hf);        // lane hf holds head hf's sum
    float v = acc / sf + b1[lane];
    helu[(size_t)n * 64 + lane] = (v > 0.f) ? v : (__expf(v) - 1.f);   // ELU
}

// ---------------- GEMM2: h2 = helu @ W2 (+ scalar attention dots) ----------------
__global__ __launch_bounds__(256) void gemm2_kernel(
    const float* __restrict__ hin, const float* __restrict__ W2,
    const float* __restrict__ att_src2, const float* __restrict__ att_dst2,
    float* __restrict__ h2, float* __restrict__ a_src, float* __restrict__ a_dst, int N)
{
    __shared__ float4 Wl[16 * 40];
    int tid = threadIdx.x;
    for (int i = tid; i < 16 * 40; i += 256) {
        int k4 = i / 40, c = i - k4 * 40;
        const float* wp = W2 + (size_t)(k4 * 4) * 40 + c;
        Wl[i] = make_float4(wp[0], wp[40], wp[80], wp[120]);
    }
    __syncthreads();

    int lane = tid & 63, w = tid >> 6;
    int row0 = blockIdx.x * 32 + w * 8;
    if (row0 >= N) return;
    int nrow = min(8, N - row0);
    int col = (lane < 40) ? lane : 0;

    const float4* xb = (const float4*)(hin + (size_t)row0 * 64);
    int ro[8];
#pragma unroll
    for (int r = 0; r < 8; ++r) ro[r] = min(r, nrow - 1) * 16;

    float acc[8] = {0.f, 0.f, 0.f, 0.f, 0.f, 0.f, 0.f, 0.f};
#pragma unroll 2
    for (int k4 = 0; k4 < 16; ++k4) {
        float4 wv = Wl[k4 * 40 + col];
#pragma unroll
        for (int r = 0; r < 8; ++r) {
            float4 xv = xb[ro[r] + k4];
            acc[r] = fmaf(xv.x, wv.x, fmaf(xv.y, wv.y, fmaf(xv.z, wv.z, fmaf(xv.w, wv.w, acc[r]))));
        }
    }

    float asv = (lane < 40) ? att_src2[lane] : 0.f;
    float adv = (lane < 40) ? att_dst2[lane] : 0.f;
#pragma unroll
    for (int r = 0; r < 8; ++r) {
        if (r >= nrow) break;
        float v = acc[r];
        if (lane < 40) h2[(size_t)(row0 + r) * 40 + lane] = v;
        float ts = v * asv, td = v * adv;
        for (int st = 1; st < 64; st <<= 1) { ts += __shfl_xor(ts, st); td += __shfl_xor(td, st); }
        if (lane == 0) { a_src[row0 + r] = ts; a_dst[row0 + r] = td; }
    }
}

// ---------------- layer-2 aggregate (single pass) + bias + log_softmax ----------------
__global__ __launch_bounds__(256) void agg2_kernel(
    const float* __restrict__ h2, const float* __restrict__ a_src, const float* __restrict__ a_dst,
    const int* __restrict__ off, const int* __restrict__ deg, const int* __restrict__ csr,
    const float* __restrict__ b2, float* __restrict__ out, int N)
{
    int wid = (blockIdx.x * 256 + threadIdx.x) >> 6;
    int lane = threadIdx.x & 63;
    if (wid >= N) return;
    int n = wid;
    int o = off[n], d = deg[n];
    int cl = (lane < 40) ? lane : 0;

    float adst = a_dst[n];
    float p_self = __expf(leaky(a_src[n] + adst));
    float s = (lane == 0) ? p_self : 0.f;
    float acc = p_self * h2[(size_t)n * 40 + cl];   // self loop (lanes>=40 dup col0, unused)

    for (int base = 0; base < d; base += 64) {
        int idx = base + lane;
        int sv = (idx < d) ? csr[o + idx] : 0;
        float pv = 0.f;
        if (idx < d) pv = __expf(leaky(a_src[sv] + adst));
        s += pv;
        int lim = min(64, d - base);
        for (int j = 0; j < lim; ++j) {
            int sj = __shfl(sv, j);
            float alpha = __shfl(pv, j);
            acc = fmaf(alpha, h2[(size_t)sj * 40 + cl], acc);
        }
    }
    for (int st = 1; st < 64; st <<= 1) s += __shfl_xor(s, st);

    float v = (lane < 40) ? (acc / s + b2[lane]) : -INFINITY;
    float mx = v;
    for (int st = 1; st < 64; st <<= 1) mx = fmaxf(mx, __shfl_xor(mx, st));
    float ex = (lane < 40) ? __expf(v - mx) : 0.f;
    float se = ex;
    for (int st = 1; st < 64; st <<= 1) se += __shfl_xor(se, st);
    if (lane < 40) out[(size_t)n * 40 + lane] = v - mx - logf(se);
}

extern "C" void kernel_launch(void* const* d_in, const int* in_sizes, int n_in,
                              void* d_out, int out_size, void* d_ws, size_t ws_size,
                              hipStream_t stream) {
    const float* x        = (const float*)d_in[0];
    const int*   ei       = (const int*)d_in[1];
    const float* W1       = (const float*)d_in[2];
    const float* att_src1 = (const float*)d_in[3];
    const float* att_dst1 = (const float*)d_in[4];
    const float* b1       = (const float*)d_in[5];
    const float* W2       = (const float*)d_in[6];
    const float* att_src2 = (const float*)d_in[7];
    const float* att_dst2 = (const float*)d_in[8];
    const float* b2       = (const float*)d_in[9];
    float* out = (float*)d_out;

    int N = in_sizes[0] / 128;
    int E = in_sizes[1] / 2;
    const int* src = ei;
    const int* dst = ei + E;

    // workspace carve (all within d_ws)
    char* w = (char*)d_ws;
    auto alloc = [&](size_t bytes) { void* p = (void*)w; w += (bytes + 255) & ~(size_t)255; return p; };
    float* h1   = (float*)alloc((size_t)N * 64 * 4);
    float* helu = (float*)alloc((size_t)N * 64 * 4);
    float* as1  = (float*)alloc((size_t)N * 8 * 4);
    float* ad1  = (float*)alloc((size_t)N * 8 * 4);
    int*   degv = (int*)alloc((size_t)N * 4);
    int*   cur  = (int*)alloc((size_t)N * 4);
    int*   offv = (int*)alloc((size_t)(N + 1) * 4);
    int*   bsum = (int*)alloc(1024 * 4);
    int*   csr  = (int*)alloc((size_t)E * 4);
    // layer-2 buffers alias layer-1 ones that are dead by then:
    float* h2  = h1;          // agg1 finished reading h1 before gemm2 writes h2
    float* as2 = as1;         // as1/ad1 dead after agg1
    float* ad2 = ad1;

    hipMemsetAsync(degv, 0, (size_t)N * 4, stream);
    hipMemsetAsync(cur, 0, (size_t)N * 4, stream);

    int eb = (E + 255) / 256;
    int nb = (N + 255) / 256;
    deg_kernel<<<eb, 256, 0, stream>>>(dst, degv, E);
    scan_block<<<nb, 256, 0, stream>>>(degv, offv, bsum, N);
    scan_aux<<<1, 1024, 0, stream>>>(bsum, nb);
    scan_add<<<nb, 256, 0, stream>>>(offv, bsum, N);
    scatter_kernel<<<eb, 256, 0, stream>>>(src, dst, offv, cur, csr, E);

    gemm1_kernel<<<(N + 31) / 32, 256, 0, stream>>>(x, W1, att_src1, att_dst1, h1, as1, ad1, N);
    agg1_kernel<<<(N + 3) / 4, 256, 0, stream>>>(h1, as1, ad1, offv, degv, csr, b1, helu, N);
    gemm2_kernel<<<(N + 31) / 32, 256, 0, stream>>>(helu, W2, att_src2, att_dst2, h2, as2, ad2, N);
    agg2_kernel<<<(N + 3) / 4, 256, 0, stream>>>(h2, as2, ad2, offv, degv, csr, b2, out, N);
}

// Round 3
// 461.348 us; speedup vs baseline: 1.5619x; 1.4865x over previous
//
#include <hip/hip_runtime.h>
#include <math.h>

#define NEG_SLOPE 0.2f

typedef __attribute__((ext_vector_type(8))) short short8;
typedef __attribute__((ext_vector_type(4))) float f32x4;

__device__ __forceinline__ float leaky(float x) { return x > 0.f ? x : NEG_SLOPE * x; }

// fp32 -> bf16 (RNE)
__device__ __forceinline__ short f2bf(float f) {
    union { float f; unsigned u; } v; v.f = f;
    unsigned r = v.u + 0x7fffu + ((v.u >> 16) & 1u);
    return (short)(r >> 16);
}
__device__ __forceinline__ float bf2f(unsigned short s) {
    union { unsigned u; float f; } v; v.u = ((unsigned)s) << 16;
    return v.f;
}

// ---------------- CSR build ----------------
__global__ void deg_kernel(const int* __restrict__ dst, int* __restrict__ deg, int E) {
    int e = blockIdx.x * 256 + threadIdx.x;
    if (e < E) atomicAdd(&deg[dst[e]], 1);
}

__global__ __launch_bounds__(256) void scan_block(const int* __restrict__ deg,
                                                  int* __restrict__ off,
                                                  int* __restrict__ bsum, int N) {
    __shared__ int sh[256];
    int t = threadIdx.x;
    int i = blockIdx.x * 256 + t;
    int v = (i < N) ? deg[i] : 0;
    sh[t] = v; __syncthreads();
    for (int s = 1; s < 256; s <<= 1) {
        int add = (t >= s) ? sh[t - s] : 0;
        __syncthreads();
        sh[t] += add;
        __syncthreads();
    }
    if (i < N) off[i] = sh[t] - v;        // exclusive
    if (t == 255) bsum[blockIdx.x] = sh[255];
}

__global__ __launch_bounds__(1024) void scan_aux(int* __restrict__ bsum, int nb) {
    __shared__ int sh[1024];
    int t = threadIdx.x;
    int v = (t < nb) ? bsum[t] : 0;
    sh[t] = v; __syncthreads();
    for (int s = 1; s < 1024; s <<= 1) {
        int add = (t >= s) ? sh[t - s] : 0;
        __syncthreads();
        sh[t] += add;
        __syncthreads();
    }
    if (t < nb) bsum[t] = sh[t] - v;      // exclusive
}

__global__ void scan_add(int* __restrict__ off, const int* __restrict__ bsum, int N) {
    int i = blockIdx.x * 256 + threadIdx.x;
    if (i < N) off[i] += bsum[blockIdx.x];
}

__global__ void scatter_kernel(const int* __restrict__ src, const int* __restrict__ dst,
                               const int* __restrict__ off, int* __restrict__ cur,
                               int* __restrict__ csr, int E) {
    int e = blockIdx.x * 256 + threadIdx.x;
    if (e < E) {
        int d = dst[e];
        int p = atomicAdd(&cur[d], 1);
        csr[off[d] + p] = src[e];
    }
}

// ---------------- GEMM1 (MFMA): h1 = bf16(x @ W1), dots in fp32 ----------------
// block 256 = 4 waves, wave = 32 rows x 64 cols (2 row-tiles x 4 col-tiles of 16x16x32)
__global__ __launch_bounds__(256) void gemm1_mfma(
    const float* __restrict__ x, const float* __restrict__ W1,
    const float* __restrict__ att_src, const float* __restrict__ att_dst,
    unsigned short* __restrict__ h1, float* __restrict__ a_src, float* __restrict__ a_dst, int N)
{
    __shared__ short Bl[16 * 64 * 8];   // 16 B-frags (ct,s), 16 KB
    __shared__ float Cs[4][32 * 64];    // fp32 C stage, 32 KB
    int tid = threadIdx.x;
    // pre-swizzle W1 into MFMA B-fragment order: frag[(ct*4+s)][lane][j] = W1[k][col]
    for (int f0 = tid; f0 < 1024; f0 += 256) {
        int lane = f0 & 63, s = (f0 >> 6) & 3, ct = f0 >> 8;
        int kb = s * 32 + ((lane >> 4) << 3);
        int col = ct * 16 + (lane & 15);
        short* dp = &Bl[f0 * 8];
#pragma unroll
        for (int j = 0; j < 8; ++j) dp[j] = f2bf(W1[(kb + j) * 64 + col]);
    }
    __syncthreads();

    int lane = tid & 63, w = tid >> 6;
    int row0 = blockIdx.x * 128 + w * 32;
    int ra = min(row0 + (lane & 15), N - 1);
    int rb = min(row0 + 16 + (lane & 15), N - 1);
    const float* pa = x + (size_t)ra * 128 + ((lane >> 4) << 3);
    const float* pb = x + (size_t)rb * 128 + ((lane >> 4) << 3);

    f32x4 acc[2][4];
#pragma unroll
    for (int i = 0; i < 2; ++i)
#pragma unroll
        for (int j = 0; j < 4; ++j) acc[i][j] = (f32x4){0.f, 0.f, 0.f, 0.f};

#pragma unroll
    for (int s = 0; s < 4; ++s) {
        float4 a0 = *(const float4*)(pa + s * 32);
        float4 a1 = *(const float4*)(pa + s * 32 + 4);
        float4 c0 = *(const float4*)(pb + s * 32);
        float4 c1 = *(const float4*)(pb + s * 32 + 4);
        short8 af, cf;
        af[0] = f2bf(a0.x); af[1] = f2bf(a0.y); af[2] = f2bf(a0.z); af[3] = f2bf(a0.w);
        af[4] = f2bf(a1.x); af[5] = f2bf(a1.y); af[6] = f2bf(a1.z); af[7] = f2bf(a1.w);
        cf[0] = f2bf(c0.x); cf[1] = f2bf(c0.y); cf[2] = f2bf(c0.z); cf[3] = f2bf(c0.w);
        cf[4] = f2bf(c1.x); cf[5] = f2bf(c1.y); cf[6] = f2bf(c1.z); cf[7] = f2bf(c1.w);
#pragma unroll
        for (int ct = 0; ct < 4; ++ct) {
            short8 wf = *(const short8*)&Bl[((ct * 4 + s) * 64 + lane) * 8];
            acc[0][ct] = __builtin_amdgcn_mfma_f32_16x16x32_bf16(af, wf, acc[0][ct], 0, 0, 0);
            acc[1][ct] = __builtin_amdgcn_mfma_f32_16x16x32_bf16(cf, wf, acc[1][ct], 0, 0, 0);
        }
    }

    // stage fp32 C to LDS (C layout: col=lane&15, row=(lane>>4)*4+reg)
    float* cs = &Cs[w][0];
#pragma unroll
    for (int rt = 0; rt < 2; ++rt)
#pragma unroll
        for (int ct = 0; ct < 4; ++ct)
#pragma unroll
            for (int r = 0; r < 4; ++r) {
                int row = rt * 16 + ((lane >> 4) << 2) + r;
                int col = ct * 16 + (lane & 15);
                cs[row * 64 + col] = acc[rt][ct][r];
            }
    __syncthreads();

    // row-layout epilogue: bf16 h1 store + fp32 attention dots
    float asv = att_src[lane], adv = att_dst[lane];
    for (int r = 0; r < 32; ++r) {
        int row = row0 + r;
        float v = cs[r * 64 + lane];
        float ts = v * asv, td = v * adv;
        ts += __shfl_xor(ts, 1); ts += __shfl_xor(ts, 2); ts += __shfl_xor(ts, 4);
        td += __shfl_xor(td, 1); td += __shfl_xor(td, 2); td += __shfl_xor(td, 4);
        if (row < N) {
            h1[(size_t)row * 64 + lane] = (unsigned short)f2bf(v);
            if ((lane & 7) == 0) {
                a_src[row * 8 + (lane >> 3)] = ts;
                a_dst[row * 8 + (lane >> 3)] = td;
            }
        }
    }
}

// ---------------- layer-1 aggregate (bf16 h1, batched gathers) ----------------
__global__ __launch_bounds__(256) void agg1_kernel(
    const unsigned short* __restrict__ h1, const float* __restrict__ a_src, const float* __restrict__ a_dst,
    const int* __restrict__ off, const int* __restrict__ deg, const int* __restrict__ csr,
    const float* __restrict__ b1, unsigned short* __restrict__ helu, int N)
{
    int n = (blockIdx.x * 256 + threadIdx.x) >> 6;
    int lane = threadIdx.x & 63;
    if (n >= N) return;
    int o = off[n], d = deg[n];
    int h8 = lane & 7, g = lane >> 3, hf = lane >> 3;

    float adst = a_dst[n * 8 + h8];
    float pself = __expf(leaky(a_src[n * 8 + h8] + adst));
    float s = (g == 0) ? pself : 0.f;
    float acc = __shfl(pself, hf) * bf2f(h1[(size_t)n * 64 + lane]);

    for (int base = 0; base < d; base += 64) {
        int idx = base + lane;
        int sv = (idx < d) ? csr[o + idx] : 0;
        int lim = min(64, d - base);
        int tmax = (lim + 7) >> 3;
        for (int t = 0; t < tmax; ++t) {
            int eidx = t * 8 + g;
            int srcn_a = __shfl(sv, eidx);
            float p = 0.f;
            if (eidx < lim) p = __expf(leaky(a_src[srcn_a * 8 + h8] + adst));
            s += p;
            // 8 independent feature gathers in flight (p=0 masks OOB edges)
#pragma unroll
            for (int j = 0; j < 8; ++j) {
                int srcn = __shfl(sv, t * 8 + j);
                float alpha = __shfl(p, j * 8 + hf);
                acc = fmaf(alpha, bf2f(h1[(size_t)srcn * 64 + lane]), acc);
            }
        }
    }
    s += __shfl_xor(s, 8); s += __shfl_xor(s, 16); s += __shfl_xor(s, 32);
    float sf = __shfl(s, hf);
    float v = acc / sf + b1[lane];
    helu[(size_t)n * 64 + lane] = (unsigned short)f2bf((v > 0.f) ? v : (__expf(v) - 1.f));
}

// ---------------- GEMM2 (MFMA): h2 = bf16(helu @ W2), scalar dots fp32 ----------------
__global__ __launch_bounds__(256) void gemm2_mfma(
    const unsigned short* __restrict__ hin, const float* __restrict__ W2,
    const float* __restrict__ att_src2, const float* __restrict__ att_dst2,
    unsigned short* __restrict__ h2, float* __restrict__ a_src, float* __restrict__ a_dst, int N)
{
    __shared__ short Bl[6 * 64 * 8];    // 6 B-frags (3 ct x 2 s), 6 KB
    __shared__ float Cs[4][32 * 48];    // 24 KB
    int tid = threadIdx.x;
    for (int f0 = tid; f0 < 384; f0 += 256) {
        int lane = f0 & 63; int fr = f0 >> 6; int s = fr & 1, ct = fr >> 1;
        int kb = s * 32 + ((lane >> 4) << 3);
        int col = ct * 16 + (lane & 15);
        short* dp = &Bl[f0 * 8];
#pragma unroll
        for (int j = 0; j < 8; ++j) dp[j] = (col < 40) ? f2bf(W2[(kb + j) * 40 + col]) : (short)0;
    }
    __syncthreads();

    int lane = tid & 63, w = tid >> 6;
    int row0 = blockIdx.x * 128 + w * 32;
    int ra = min(row0 + (lane & 15), N - 1);
    int rb = min(row0 + 16 + (lane & 15), N - 1);
    const unsigned short* pa = hin + (size_t)ra * 64 + ((lane >> 4) << 3);
    const unsigned short* pb = hin + (size_t)rb * 64 + ((lane >> 4) << 3);

    f32x4 acc[2][3];
#pragma unroll
    for (int i = 0; i < 2; ++i)
#pragma unroll
        for (int j = 0; j < 3; ++j) acc[i][j] = (f32x4){0.f, 0.f, 0.f, 0.f};

#pragma unroll
    for (int s = 0; s < 2; ++s) {
        short8 af = *(const short8*)(pa + s * 32);
        short8 cf = *(const short8*)(pb + s * 32);
#pragma unroll
        for (int ct = 0; ct < 3; ++ct) {
            short8 wf = *(const short8*)&Bl[((ct * 2 + s) * 64 + lane) * 8];
            acc[0][ct] = __builtin_amdgcn_mfma_f32_16x16x32_bf16(af, wf, acc[0][ct], 0, 0, 0);
            acc[1][ct] = __builtin_amdgcn_mfma_f32_16x16x32_bf16(cf, wf, acc[1][ct], 0, 0, 0);
        }
    }

    float* cs = &Cs[w][0];
#pragma unroll
    for (int rt = 0; rt < 2; ++rt)
#pragma unroll
        for (int ct = 0; ct < 3; ++ct)
#pragma unroll
            for (int r = 0; r < 4; ++r) {
                int row = rt * 16 + ((lane >> 4) << 2) + r;
                int col = ct * 16 + (lane & 15);
                cs[row * 48 + col] = acc[rt][ct][r];
            }
    __syncthreads();

    float asv = (lane < 40) ? att_src2[lane] : 0.f;
    float adv = (lane < 40) ? att_dst2[lane] : 0.f;
    for (int r = 0; r < 32; ++r) {
        int row = row0 + r;
        float v = (lane < 48) ? cs[r * 48 + lane] : 0.f;
        float ts = (lane < 40) ? v * asv : 0.f;
        float td = (lane < 40) ? v * adv : 0.f;
        for (int st = 1; st < 64; st <<= 1) { ts += __shfl_xor(ts, st); td += __shfl_xor(td, st); }
        if (row < N) {
            if (lane < 40) h2[(size_t)row * 40 + lane] = (unsigned short)f2bf(v);
            if (lane == 0) { a_src[row] = ts; a_dst[row] = td; }
        }
    }
}

// ---------------- layer-2 aggregate + bias + log_softmax (bf16 h2) ----------------
__global__ __launch_bounds__(256) void agg2_kernel(
    const unsigned short* __restrict__ h2, const float* __restrict__ a_src, const float* __restrict__ a_dst,
    const int* __restrict__ off, const int* __restrict__ deg, const int* __restrict__ csr,
    const float* __restrict__ b2, float* __restrict__ out, int N)
{
    int n = (blockIdx.x * 256 + threadIdx.x) >> 6;
    int lane = threadIdx.x & 63;
    if (n >= N) return;
    int o = off[n], d = deg[n];
    int cl = (lane < 40) ? lane : 0;

    float adst = a_dst[n];
    float pself = __expf(leaky(a_src[n] + adst));
    float acc = pself * bf2f(h2[(size_t)n * 40 + cl]);
    float sp = 0.f;

    for (int base = 0; base < d; base += 64) {
        int idx = base + lane;
        int sv = (idx < d) ? csr[o + idx] : 0;
        float pv = 0.f;
        if (idx < d) pv = __expf(leaky(a_src[sv] + adst));
        sp += pv;
        int lim = min(64, d - base);
        for (int j = 0; j < lim; j += 4) {
#pragma unroll
            for (int u = 0; u < 4; ++u) {
                int srcn = __shfl(sv, j + u);
                float alpha = (j + u < lim) ? __shfl(pv, j + u) : 0.f;
                acc = fmaf(alpha, bf2f(h2[(size_t)srcn * 40 + cl]), acc);
            }
        }
    }
    for (int st = 1; st < 64; st <<= 1) sp += __shfl_xor(sp, st);
    float stot = sp + pself;

    float v = (lane < 40) ? (acc / stot + b2[lane]) : -INFINITY;
    float mx = v;
    for (int st = 1; st < 64; st <<= 1) mx = fmaxf(mx, __shfl_xor(mx, st));
    float ex = (lane < 40) ? __expf(v - mx) : 0.f;
    float se = ex;
    for (int st = 1; st < 64; st <<= 1) se += __shfl_xor(se, st);
    if (lane < 40) out[(size_t)n * 40 + lane] = v - mx - logf(se);
}

extern "C" void kernel_launch(void* const* d_in, const int* in_sizes, int n_in,
                              void* d_out, int out_size, void* d_ws, size_t ws_size,
                              hipStream_t stream) {
    const float* x        = (const float*)d_in[0];
    const int*   ei       = (const int*)d_in[1];
    const float* W1       = (const float*)d_in[2];
    const float* att_src1 = (const float*)d_in[3];
    const float* att_dst1 = (const float*)d_in[4];
    const float* b1       = (const float*)d_in[5];
    const float* W2       = (const float*)d_in[6];
    const float* att_src2 = (const float*)d_in[7];
    const float* att_dst2 = (const float*)d_in[8];
    const float* b2       = (const float*)d_in[9];
    float* out = (float*)d_out;

    int N = in_sizes[0] / 128;
    int E = in_sizes[1] / 2;
    const int* src = ei;
    const int* dst = ei + E;

    char* w = (char*)d_ws;
    auto alloc = [&](size_t bytes) { void* p = (void*)w; w += (bytes + 255) & ~(size_t)255; return p; };
    unsigned short* h1   = (unsigned short*)alloc((size_t)N * 64 * 2);
    unsigned short* helu = (unsigned short*)alloc((size_t)N * 64 * 2);
    float* as1  = (float*)alloc((size_t)N * 8 * 4);
    float* ad1  = (float*)alloc((size_t)N * 8 * 4);
    int*   degv = (int*)alloc((size_t)N * 4);
    int*   cur  = (int*)alloc((size_t)N * 4);
    int*   offv = (int*)alloc((size_t)(N + 1) * 4);
    int*   bsum = (int*)alloc(1024 * 4);
    int*   csr  = (int*)alloc((size_t)E * 4);
    // layer-2 aliases (layer-1 buffers dead by then)
    unsigned short* h2 = h1;
    float* as2 = as1;
    float* ad2 = ad1;

    hipMemsetAsync(degv, 0, (size_t)N * 4, stream);
    hipMemsetAsync(cur, 0, (size_t)N * 4, stream);

    int eb = (E + 255) / 256;
    int nb = (N + 255) / 256;
    deg_kernel<<<eb, 256, 0, stream>>>(dst, degv, E);
    scan_block<<<nb, 256, 0, stream>>>(degv, offv, bsum, N);
    scan_aux<<<1, 1024, 0, stream>>>(bsum, nb);
    scan_add<<<nb, 256, 0, stream>>>(offv, bsum, N);
    scatter_kernel<<<eb, 256, 0, stream>>>(src, dst, offv, cur, csr, E);

    int gb = (N + 127) / 128;
    gemm1_mfma<<<gb, 256, 0, stream>>>(x, W1, att_src1, att_dst1, h1, as1, ad1, N);
    agg1_kernel<<<(N + 3) / 4, 256, 0, stream>>>(h1, as1, ad1, offv, degv, csr, b1, helu, N);
    gemm2_mfma<<<gb, 256, 0, stream>>>(helu, W2, att_src2, att_dst2, h2, as2, ad2, N);
    agg2_kernel<<<(N + 3) / 4, 256, 0, stream>>>(h2, as2, ad2, offv, degv, csr, b2, out, N);
}

// Round 4
// 341.616 us; speedup vs baseline: 2.1093x; 1.3505x over previous
//
#include <hip/hip_runtime.h>
#include <math.h>

#define NEG_SLOPE 0.2f

typedef __attribute__((ext_vector_type(8))) short short8;
typedef __attribute__((ext_vector_type(4))) float f32x4;

__device__ __forceinline__ float leaky(float x) { return x > 0.f ? x : NEG_SLOPE * x; }

// fp32 -> bf16 (RNE)
__device__ __forceinline__ short f2bf(float f) {
    union { float f; unsigned u; } v; v.f = f;
    unsigned r = v.u + 0x7fffu + ((v.u >> 16) & 1u);
    return (short)(r >> 16);
}
__device__ __forceinline__ float bf2f(unsigned short s) {
    union { unsigned u; float f; } v; v.u = ((unsigned)s) << 16;
    return v.f;
}

// ================= CSR build: workgroup-exclusive counting sort =================
// bucket = dst >> 7 (128 nodes per bucket). G edge-chunks. Each (bucket, chunk)
// pair gets an exclusive contiguous output range -> no cross-XCD cacheline
// sharing -> no write amplification (the round-3 scatter wrote 107 MB of HBM
// for 6.4 MB of payload because adjacent slots were claimed by random XCDs).
#define GCHUNK 256
#define NB_MAX 1024   // supports N <= 131072

// Phase A: per-chunk bucket histogram + global bucket totals
__global__ __launch_bounds__(256) void hist_kernel(const int* __restrict__ dst, int E, int nbuck,
                                                   int* __restrict__ histG, int* __restrict__ total) {
    __shared__ int lh[NB_MAX];
    int g = blockIdx.x, t = threadIdx.x;
    for (int i = t; i < nbuck; i += 256) lh[i] = 0;
    __syncthreads();
    int ce = (E + GCHUNK - 1) / GCHUNK;
    int e0 = g * ce, e1 = min(e0 + ce, E);
    for (int e = e0 + t; e < e1; e += 256)
        atomicAdd(&lh[dst[e] >> 7], 1);
    __syncthreads();
    for (int i = t; i < nbuck; i += 256) {
        histG[i * GCHUNK + g] = lh[i];
        if (lh[i]) atomicAdd(&total[i], lh[i]);
    }
}

// Phase B1: exclusive scan of bucket totals -> bbase (nbuck+1 entries)
__global__ __launch_bounds__(1024) void bscan_kernel(const int* __restrict__ total,
                                                     int* __restrict__ bbase, int nbuck) {
    __shared__ int sh[1024];
    int t = threadIdx.x;
    int v = (t < nbuck) ? total[t] : 0;
    sh[t] = v; __syncthreads();
    for (int s = 1; s < 1024; s <<= 1) {
        int add = (t >= s) ? sh[t - s] : 0;
        __syncthreads();
        sh[t] += add;
        __syncthreads();
    }
    if (t < nbuck) bbase[t] = sh[t] - v;
    if (t == nbuck - 1) bbase[nbuck] = sh[t];
}

// Phase B2: per-bucket exclusive scan over chunks -> startG[b][g]
__global__ __launch_bounds__(256) void bstart_kernel(const int* __restrict__ histG,
                                                     const int* __restrict__ bbase,
                                                     int* __restrict__ startG, int nbuck) {
    __shared__ int sh[256];
    int b = blockIdx.x, t = threadIdx.x;
    int v = histG[b * GCHUNK + t];
    sh[t] = v; __syncthreads();
    for (int s = 1; s < 256; s <<= 1) {
        int add = (t >= s) ? sh[t - s] : 0;
        __syncthreads();
        sh[t] += add;
        __syncthreads();
    }
    startG[b * GCHUNK + t] = bbase[b] + sh[t] - v;
}

// Phase C: scatter (src,dst) pairs into bucket-grouped pairbuf (workgroup-exclusive ranges)
__global__ __launch_bounds__(256) void bucket_scatter(const int* __restrict__ src,
                                                      const int* __restrict__ dst, int E, int nbuck,
                                                      const int* __restrict__ startG,
                                                      int2* __restrict__ pairbuf) {
    __shared__ int cur[NB_MAX];
    int g = blockIdx.x, t = threadIdx.x;
    for (int i = t; i < nbuck; i += 256) cur[i] = startG[i * GCHUNK + g];
    __syncthreads();
    int ce = (E + GCHUNK - 1) / GCHUNK;
    int e0 = g * ce, e1 = min(e0 + ce, E);
    for (int e = e0 + t; e < e1; e += 256) {
        int d = dst[e], b = d >> 7;
        int pos = atomicAdd(&cur[b], 1);
        pairbuf[pos] = make_int2(src[e], d);
    }
}

// Phase D: per-bucket node-level placement; also emits deg[] and off[]
__global__ __launch_bounds__(256) void bucket_place(const int2* __restrict__ pairbuf,
                                                    const int* __restrict__ bbase, int nbuck, int N,
                                                    int* __restrict__ deg, int* __restrict__ off,
                                                    int* __restrict__ csr) {
    __shared__ int2 stash[4096];
    __shared__ int ldeg[128], lcur[128], sh[128];
    int b = blockIdx.x, t = threadIdx.x;
    int p0 = bbase[b], p1 = bbase[b + 1];
    int cnt = p1 - p0;
    int node0 = b << 7;
    for (int i = t; i < 128; i += 256) ldeg[i] = 0;
    __syncthreads();
    for (int i = t; i < cnt; i += 256) {
        int2 pr = pairbuf[p0 + i];
        if (i < 4096) stash[i] = pr;
        atomicAdd(&ldeg[pr.y - node0], 1);
    }
    __syncthreads();
    if (t < 128) sh[t] = ldeg[t];
    __syncthreads();
    for (int s = 1; s < 128; s <<= 1) {
        int add = (t >= s && t < 128) ? sh[t - s] : 0;
        __syncthreads();
        if (t < 128) sh[t] += add;
        __syncthreads();
    }
    if (t < 128) {
        int excl = sh[t] - ldeg[t];
        int n = node0 + t;
        if (n < N) { deg[n] = ldeg[t]; off[n] = p0 + excl; }
        lcur[t] = p0 + excl;
    }
    __syncthreads();
    for (int i = t; i < cnt; i += 256) {
        int2 pr = (i < 4096) ? stash[i] : pairbuf[p0 + i];
        int pos = atomicAdd(&lcur[pr.y - node0], 1);
        csr[pos] = pr.x;
    }
}

// ---------------- GEMM1 (MFMA): h1 = bf16(x @ W1), dots in fp32 ----------------
__global__ __launch_bounds__(256) void gemm1_mfma(
    const float* __restrict__ x, const float* __restrict__ W1,
    const float* __restrict__ att_src, const float* __restrict__ att_dst,
    unsigned short* __restrict__ h1, float* __restrict__ a_src, float* __restrict__ a_dst, int N)
{
    __shared__ short Bl[16 * 64 * 8];   // 16 B-frags (ct,s), 16 KB
    __shared__ float Cs[4][32 * 64];    // fp32 C stage, 32 KB
    int tid = threadIdx.x;
    for (int f0 = tid; f0 < 1024; f0 += 256) {
        int lane = f0 & 63, s = (f0 >> 6) & 3, ct = f0 >> 8;
        int kb = s * 32 + ((lane >> 4) << 3);
        int col = ct * 16 + (lane & 15);
        short* dp = &Bl[f0 * 8];
#pragma unroll
        for (int j = 0; j < 8; ++j) dp[j] = f2bf(W1[(kb + j) * 64 + col]);
    }
    __syncthreads();

    int lane = tid & 63, w = tid >> 6;
    int row0 = blockIdx.x * 128 + w * 32;
    int ra = min(row0 + (lane & 15), N - 1);
    int rb = min(row0 + 16 + (lane & 15), N - 1);
    const float* pa = x + (size_t)ra * 128 + ((lane >> 4) << 3);
    const float* pb = x + (size_t)rb * 128 + ((lane >> 4) << 3);

    f32x4 acc[2][4];
#pragma unroll
    for (int i = 0; i < 2; ++i)
#pragma unroll
        for (int j = 0; j < 4; ++j) acc[i][j] = (f32x4){0.f, 0.f, 0.f, 0.f};

#pragma unroll
    for (int s = 0; s < 4; ++s) {
        float4 a0 = *(const float4*)(pa + s * 32);
        float4 a1 = *(const float4*)(pa + s * 32 + 4);
        float4 c0 = *(const float4*)(pb + s * 32);
        float4 c1 = *(const float4*)(pb + s * 32 + 4);
        short8 af, cf;
        af[0] = f2bf(a0.x); af[1] = f2bf(a0.y); af[2] = f2bf(a0.z); af[3] = f2bf(a0.w);
        af[4] = f2bf(a1.x); af[5] = f2bf(a1.y); af[6] = f2bf(a1.z); af[7] = f2bf(a1.w);
        cf[0] = f2bf(c0.x); cf[1] = f2bf(c0.y); cf[2] = f2bf(c0.z); cf[3] = f2bf(c0.w);
        cf[4] = f2bf(c1.x); cf[5] = f2bf(c1.y); cf[6] = f2bf(c1.z); cf[7] = f2bf(c1.w);
#pragma unroll
        for (int ct = 0; ct < 4; ++ct) {
            short8 wf = *(const short8*)&Bl[((ct * 4 + s) * 64 + lane) * 8];
            acc[0][ct] = __builtin_amdgcn_mfma_f32_16x16x32_bf16(af, wf, acc[0][ct], 0, 0, 0);
            acc[1][ct] = __builtin_amdgcn_mfma_f32_16x16x32_bf16(cf, wf, acc[1][ct], 0, 0, 0);
        }
    }

    float* cs = &Cs[w][0];
#pragma unroll
    for (int rt = 0; rt < 2; ++rt)
#pragma unroll
        for (int ct = 0; ct < 4; ++ct)
#pragma unroll
            for (int r = 0; r < 4; ++r) {
                int row = rt * 16 + ((lane >> 4) << 2) + r;
                int col = ct * 16 + (lane & 15);
                cs[row * 64 + col] = acc[rt][ct][r];
            }
    __syncthreads();

    float asv = att_src[lane], adv = att_dst[lane];
    for (int r = 0; r < 32; ++r) {
        int row = row0 + r;
        float v = cs[r * 64 + lane];
        float ts = v * asv, td = v * adv;
        ts += __shfl_xor(ts, 1); ts += __shfl_xor(ts, 2); ts += __shfl_xor(ts, 4);
        td += __shfl_xor(td, 1); td += __shfl_xor(td, 2); td += __shfl_xor(td, 4);
        if (row < N) {
            h1[(size_t)row * 64 + lane] = (unsigned short)f2bf(v);
            if ((lane & 7) == 0) {
                a_src[row * 8 + (lane >> 3)] = ts;
                a_dst[row * 8 + (lane >> 3)] = td;
            }
        }
    }
}

// ---------------- layer-1 aggregate (bf16 h1, batched gathers) ----------------
__global__ __launch_bounds__(256) void agg1_kernel(
    const unsigned short* __restrict__ h1, const float* __restrict__ a_src, const float* __restrict__ a_dst,
    const int* __restrict__ off, const int* __restrict__ deg, const int* __restrict__ csr,
    const float* __restrict__ b1, unsigned short* __restrict__ helu, int N)
{
    int n = (blockIdx.x * 256 + threadIdx.x) >> 6;
    int lane = threadIdx.x & 63;
    if (n >= N) return;
    int o = off[n], d = deg[n];
    int h8 = lane & 7, g = lane >> 3, hf = lane >> 3;

    float adst = a_dst[n * 8 + h8];
    float pself = __expf(leaky(a_src[n * 8 + h8] + adst));
    float s = (g == 0) ? pself : 0.f;
    float acc = __shfl(pself, hf) * bf2f(h1[(size_t)n * 64 + lane]);

    for (int base = 0; base < d; base += 64) {
        int idx = base + lane;
        int sv = (idx < d) ? csr[o + idx] : 0;
        int lim = min(64, d - base);
        int tmax = (lim + 7) >> 3;
        for (int t = 0; t < tmax; ++t) {
            int eidx = t * 8 + g;
            int srcn_a = __shfl(sv, eidx);
            float p = 0.f;
            if (eidx < lim) p = __expf(leaky(a_src[srcn_a * 8 + h8] + adst));
            s += p;
#pragma unroll
            for (int j = 0; j < 8; ++j) {
                int srcn = __shfl(sv, t * 8 + j);
                float alpha = __shfl(p, j * 8 + hf);
                acc = fmaf(alpha, bf2f(h1[(size_t)srcn * 64 + lane]), acc);
            }
        }
    }
    s += __shfl_xor(s, 8); s += __shfl_xor(s, 16); s += __shfl_xor(s, 32);
    float sf = __shfl(s, hf);
    float v = acc / sf + b1[lane];
    helu[(size_t)n * 64 + lane] = (unsigned short)f2bf((v > 0.f) ? v : (__expf(v) - 1.f));
}

// ---------------- GEMM2 (MFMA): h2 = bf16(helu @ W2), scalar dots fp32 ----------------
__global__ __launch_bounds__(256) void gemm2_mfma(
    const unsigned short* __restrict__ hin, const float* __restrict__ W2,
    const float* __restrict__ att_src2, const float* __restrict__ att_dst2,
    unsigned short* __restrict__ h2, float* __restrict__ a_src, float* __restrict__ a_dst, int N)
{
    __shared__ short Bl[6 * 64 * 8];
    __shared__ float Cs[4][32 * 48];
    int tid = threadIdx.x;
    for (int f0 = tid; f0 < 384; f0 += 256) {
        int lane = f0 & 63; int fr = f0 >> 6; int s = fr & 1, ct = fr >> 1;
        int kb = s * 32 + ((lane >> 4) << 3);
        int col = ct * 16 + (lane & 15);
        short* dp = &Bl[f0 * 8];
#pragma unroll
        for (int j = 0; j < 8; ++j) dp[j] = (col < 40) ? f2bf(W2[(kb + j) * 40 + col]) : (short)0;
    }
    __syncthreads();

    int lane = tid & 63, w = tid >> 6;
    int row0 = blockIdx.x * 128 + w * 32;
    int ra = min(row0 + (lane & 15), N - 1);
    int rb = min(row0 + 16 + (lane & 15), N - 1);
    const unsigned short* pa = hin + (size_t)ra * 64 + ((lane >> 4) << 3);
    const unsigned short* pb = hin + (size_t)rb * 64 + ((lane >> 4) << 3);

    f32x4 acc[2][3];
#pragma unroll
    for (int i = 0; i < 2; ++i)
#pragma unroll
        for (int j = 0; j < 3; ++j) acc[i][j] = (f32x4){0.f, 0.f, 0.f, 0.f};

#pragma unroll
    for (int s = 0; s < 2; ++s) {
        short8 af = *(const short8*)(pa + s * 32);
        short8 cf = *(const short8*)(pb + s * 32);
#pragma unroll
        for (int ct = 0; ct < 3; ++ct) {
            short8 wf = *(const short8*)&Bl[((ct * 2 + s) * 64 + lane) * 8];
            acc[0][ct] = __builtin_amdgcn_mfma_f32_16x16x32_bf16(af, wf, acc[0][ct], 0, 0, 0);
            acc[1][ct] = __builtin_amdgcn_mfma_f32_16x16x32_bf16(cf, wf, acc[1][ct], 0, 0, 0);
        }
    }

    float* cs = &Cs[w][0];
#pragma unroll
    for (int rt = 0; rt < 2; ++rt)
#pragma unroll
        for (int ct = 0; ct < 3; ++ct)
#pragma unroll
            for (int r = 0; r < 4; ++r) {
                int row = rt * 16 + ((lane >> 4) << 2) + r;
                int col = ct * 16 + (lane & 15);
                cs[row * 48 + col] = acc[rt][ct][r];
            }
    __syncthreads();

    float asv = (lane < 40) ? att_src2[lane] : 0.f;
    float adv = (lane < 40) ? att_dst2[lane] : 0.f;
    for (int r = 0; r < 32; ++r) {
        int row = row0 + r;
        float v = (lane < 48) ? cs[r * 48 + lane] : 0.f;
        float ts = (lane < 40) ? v * asv : 0.f;
        float td = (lane < 40) ? v * adv : 0.f;
        for (int st = 1; st < 64; st <<= 1) { ts += __shfl_xor(ts, st); td += __shfl_xor(td, st); }
        if (row < N) {
            if (lane < 40) h2[(size_t)row * 40 + lane] = (unsigned short)f2bf(v);
            if (lane == 0) { a_src[row] = ts; a_dst[row] = td; }
        }
    }
}

// ---------------- layer-2 aggregate + bias + log_softmax (bf16 h2) ----------------
__global__ __launch_bounds__(256) void agg2_kernel(
    const unsigned short* __restrict__ h2, const float* __restrict__ a_src, const float* __restrict__ a_dst,
    const int* __restrict__ off, const int* __restrict__ deg, const int* __restrict__ csr,
    const float* __restrict__ b2, float* __restrict__ out, int N)
{
    int n = (blockIdx.x * 256 + threadIdx.x) >> 6;
    int lane = threadIdx.x & 63;
    if (n >= N) return;
    int o = off[n], d = deg[n];
    int cl = (lane < 40) ? lane : 0;

    float adst = a_dst[n];
    float pself = __expf(leaky(a_src[n] + adst));
    float acc = pself * bf2f(h2[(size_t)n * 40 + cl]);
    float sp = 0.f;

    for (int base = 0; base < d; base += 64) {
        int idx = base + lane;
        int sv = (idx < d) ? csr[o + idx] : 0;
        float pv = 0.f;
        if (idx < d) pv = __expf(leaky(a_src[sv] + adst));
        sp += pv;
        int lim = min(64, d - base);
        for (int j = 0; j < lim; j += 4) {
#pragma unroll
            for (int u = 0; u < 4; ++u) {
                int srcn = __shfl(sv, j + u);
                float alpha = (j + u < lim) ? __shfl(pv, j + u) : 0.f;
                acc = fmaf(alpha, bf2f(h2[(size_t)srcn * 40 + cl]), acc);
            }
        }
    }
    for (int st = 1; st < 64; st <<= 1) sp += __shfl_xor(sp, st);
    float stot = sp + pself;

    float v = (lane < 40) ? (acc / stot + b2[lane]) : -INFINITY;
    float mx = v;
    for (int st = 1; st < 64; st <<= 1) mx = fmaxf(mx, __shfl_xor(mx, st));
    float ex = (lane < 40) ? __expf(v - mx) : 0.f;
    float se = ex;
    for (int st = 1; st < 64; st <<= 1) se += __shfl_xor(se, st);
    if (lane < 40) out[(size_t)n * 40 + lane] = v - mx - logf(se);
}

extern "C" void kernel_launch(void* const* d_in, const int* in_sizes, int n_in,
                              void* d_out, int out_size, void* d_ws, size_t ws_size,
                              hipStream_t stream) {
    const float* x        = (const float*)d_in[0];
    const int*   ei       = (const int*)d_in[1];
    const float* W1       = (const float*)d_in[2];
    const float* att_src1 = (const float*)d_in[3];
    const float* att_dst1 = (const float*)d_in[4];
    const float* b1       = (const float*)d_in[5];
    const float* W2       = (const float*)d_in[6];
    const float* att_src2 = (const float*)d_in[7];
    const float* att_dst2 = (const float*)d_in[8];
    const float* b2       = (const float*)d_in[9];
    float* out = (float*)d_out;

    int N = in_sizes[0] / 128;
    int E = in_sizes[1] / 2;
    const int* src = ei;
    const int* dst = ei + E;
    int nbuck = (N + 127) >> 7;

    char* w = (char*)d_ws;
    auto alloc = [&](size_t bytes) { void* p = (void*)w; w += (bytes + 255) & ~(size_t)255; return p; };
    unsigned short* h1   = (unsigned short*)alloc((size_t)N * 64 * 2);
    unsigned short* helu = (unsigned short*)alloc((size_t)N * 64 * 2);
    float* as1  = (float*)alloc((size_t)N * 8 * 4);
    float* ad1  = (float*)alloc((size_t)N * 8 * 4);
    int*   degv = (int*)alloc((size_t)N * 4);
    int*   offv = (int*)alloc((size_t)(N + 1) * 4);
    int*   csr  = (int*)alloc((size_t)E * 4);
    int*   histG  = (int*)alloc((size_t)nbuck * GCHUNK * 4);
    int*   startG = (int*)alloc((size_t)nbuck * GCHUNK * 4);
    int*   total  = (int*)alloc((size_t)nbuck * 4);
    int*   bbase  = (int*)alloc((size_t)(nbuck + 1) * 4);
    int2*  pairbuf = (int2*)alloc((size_t)E * 8);
    unsigned short* h2 = h1;
    float* as2 = as1;
    float* ad2 = ad1;

    hipMemsetAsync(total, 0, (size_t)nbuck * 4, stream);
    hist_kernel<<<GCHUNK, 256, 0, stream>>>(dst, E, nbuck, histG, total);
    bscan_kernel<<<1, 1024, 0, stream>>>(total, bbase, nbuck);
    bstart_kernel<<<nbuck, 256, 0, stream>>>(histG, bbase, startG, nbuck);
    bucket_scatter<<<GCHUNK, 256, 0, stream>>>(src, dst, E, nbuck, startG, pairbuf);
    bucket_place<<<nbuck, 256, 0, stream>>>(pairbuf, bbase, nbuck, N, degv, offv, csr);

    int gb = (N + 127) / 128;
    gemm1_mfma<<<gb, 256, 0, stream>>>(x, W1, att_src1, att_dst1, h1, as1, ad1, N);
    agg1_kernel<<<(N + 3) / 4, 256, 0, stream>>>(h1, as1, ad1, offv, degv, csr, b1, helu, N);
    gemm2_mfma<<<gb, 256, 0, stream>>>(helu, W2, att_src2, att_dst2, h2, as2, ad2, N);
    agg2_kernel<<<(N + 3) / 4, 256, 0, stream>>>(h2, as2, ad2, offv, degv, csr, b2, out, N);
}